// Round 18
// baseline (378.325 us; speedup 1.0000x reference)
//
#include <hip/hip_runtime.h>

#define S_ 2048
#define B_ 2
#define E_ 1024
#define H_ 16

typedef _Float16 f16x8 __attribute__((ext_vector_type(8)));
typedef _Float16 f16x4 __attribute__((ext_vector_type(4)));
typedef _Float16 f16x2 __attribute__((ext_vector_type(2)));
typedef float f32x4 __attribute__((ext_vector_type(4)));
typedef unsigned short us4_t __attribute__((ext_vector_type(4)));
typedef unsigned u32x4 __attribute__((ext_vector_type(4)));
typedef unsigned u32x2 __attribute__((ext_vector_type(2)));

static __device__ __forceinline__ unsigned short f2h(float x) {
  _Float16 h = (_Float16)x;   // RNE
  return __builtin_bit_cast(unsigned short, h);
}
static __device__ __forceinline__ unsigned pk_f16(float a, float b) {
  auto r = __builtin_amdgcn_cvt_pkrtz(a, b);   // lo=a, hi=b (RTZ - p only)
  return __builtin_bit_cast(unsigned, r);
}

// ---------------- all f32 -> fp16 conversions in ONE launch (RNE) ----------------
__global__ void k_cvt_all(const float* __restrict__ q, const float* __restrict__ k,
                          const float* __restrict__ v, const float* __restrict__ ipw,
                          const float* __restrict__ outw,
                          unsigned short* __restrict__ qx, unsigned short* __restrict__ kx,
                          unsigned short* __restrict__ vx, unsigned short* __restrict__ w3,
                          unsigned short* __restrict__ ow) {
  const int M1 = 1 << 20;
  int i = blockIdx.x * blockDim.x + threadIdx.x;
  int stp = gridDim.x * blockDim.x;
  for (; i < 4 * M1; i += stp) {
    const float* src;
    unsigned short* dst;
    int j;
    if (i < M1)            { src = q;    dst = qx; j = i; }
    else if (i < 2 * M1)   { src = k;    dst = kx; j = i - M1; }
    else if (i < 3 * M1)   { src = v;    dst = vx; j = i - 2 * M1; }
    else if (i < 3 * M1 + 786432) { src = ipw; dst = w3; j = i - 3 * M1; }
    else                   { src = outw; dst = ow; j = i - 3 * M1 - 786432; }
    f32x4 x = ((const f32x4*)src)[j];
    us4_t h;
    #pragma unroll
    for (int e = 0; e < 4; ++e) h[e] = f2h(x[e]);
    ((us4_t*)dst)[j] = h;
  }
}

// ---------------- q/k projection: plain fp16 GEMM ----------------
__launch_bounds__(256, 2)
__global__ void k_proj_qk(const unsigned short* __restrict__ qx, const unsigned short* __restrict__ kx,
                          const unsigned short* __restrict__ wqk, const float* __restrict__ bias,
                          unsigned short* __restrict__ qf, unsigned short* __restrict__ kf) {
  const int z = blockIdx.z;
  const unsigned short* A = z ? kx : qx;
  const unsigned short* W = wqk + (size_t)z * (1024 * 1024);
  unsigned short* C = z ? kf : qf;
  const float* bia = bias + z * 1024;
  const float scale = z ? 1.0f : 0.125f;

  __shared__ unsigned short sA[128][40], sB[128][40];

  const int t = threadIdx.x;
  const int wid = t >> 6, l = t & 63, g = l >> 4, c = l & 15;
  const int wr = wid >> 1, wc = wid & 1;
  const int mb = blockIdx.x * 128, nb = blockIdx.y * 128;
  const int sr = t >> 1, sc = (t & 1) * 16;

  f32x4 acc[4][4] = {};

  for (int k0 = 0; k0 < 1024; k0 += 32) {
    __syncthreads();
    {
      const unsigned short* pa = A + (size_t)(mb + sr) * 1024 + k0 + sc;
      const unsigned short* pb = W + (size_t)(nb + sr) * 1024 + k0 + sc;
      *(f16x8*)&sA[sr][sc]     = *(const f16x8*)pa;
      *(f16x8*)&sA[sr][sc + 8] = *(const f16x8*)(pa + 8);
      *(f16x8*)&sB[sr][sc]     = *(const f16x8*)pb;
      *(f16x8*)&sB[sr][sc + 8] = *(const f16x8*)(pb + 8);
    }
    __syncthreads();
    f16x8 af[4], bf[4];
    #pragma unroll
    for (int i = 0; i < 4; ++i) {
      af[i] = *(const f16x8*)&sA[wr * 64 + i * 16 + c][g * 8];
      bf[i] = *(const f16x8*)&sB[wc * 64 + i * 16 + c][g * 8];
    }
    #pragma unroll
    for (int i = 0; i < 4; ++i)
      #pragma unroll
      for (int j = 0; j < 4; ++j)
        acc[i][j] = __builtin_amdgcn_mfma_f32_16x16x32_f16(af[i], bf[j], acc[i][j], 0, 0, 0);
  }
  #pragma unroll
  for (int i = 0; i < 4; ++i)
    #pragma unroll
    for (int j = 0; j < 4; ++j)
      #pragma unroll
      for (int rr = 0; rr < 4; ++rr) {
        int m = mb + wr * 64 + i * 16 + 4 * g + rr;
        int n = nb + wc * 64 + j * 16 + c;
        float v = (acc[i][j][rr] + bia[n]) * scale;
        C[(size_t)m * 1024 + n] = f2h(v);
      }
}

// ---------------- v projection (fp16), writes V^T: VT[b][e'][j] ----------------
__launch_bounds__(256, 2)
__global__ void k_proj_v(const unsigned short* __restrict__ wv, const unsigned short* __restrict__ vx,
                         const float* __restrict__ bias, unsigned short* __restrict__ VT) {
  __shared__ unsigned short sA[128][40], sB[128][40];
  const int t = threadIdx.x;
  const int wid = t >> 6, l = t & 63, g = l >> 4, c = l & 15;
  const int wr = wid >> 1, wc = wid & 1;
  const int mb = blockIdx.x * 128;   // e' base
  const int nb = blockIdx.y * 128;   // n = b*2048 + j
  const int bb = nb >> 11;
  const int jb = nb & 2047;
  const int sr = t >> 1, sc = (t & 1) * 16;

  f32x4 acc[4][4] = {};
  for (int k0 = 0; k0 < 1024; k0 += 32) {
    __syncthreads();
    {
      const unsigned short* pa = wv + (size_t)(mb + sr) * 1024 + k0 + sc;
      const unsigned short* pb = vx + ((size_t)(jb + sr) * 2 + bb) * 1024 + k0 + sc;
      *(f16x8*)&sA[sr][sc]     = *(const f16x8*)pa;
      *(f16x8*)&sA[sr][sc + 8] = *(const f16x8*)(pa + 8);
      *(f16x8*)&sB[sr][sc]     = *(const f16x8*)pb;
      *(f16x8*)&sB[sr][sc + 8] = *(const f16x8*)(pb + 8);
    }
    __syncthreads();
    f16x8 af[4], bf[4];
    #pragma unroll
    for (int i = 0; i < 4; ++i) {
      af[i] = *(const f16x8*)&sA[wr * 64 + i * 16 + c][g * 8];
      bf[i] = *(const f16x8*)&sB[wc * 64 + i * 16 + c][g * 8];
    }
    #pragma unroll
    for (int i = 0; i < 4; ++i)
      #pragma unroll
      for (int j = 0; j < 4; ++j)
        acc[i][j] = __builtin_amdgcn_mfma_f32_16x16x32_f16(af[i], bf[j], acc[i][j], 0, 0, 0);
  }
  #pragma unroll
  for (int i = 0; i < 4; ++i)
    #pragma unroll
    for (int j = 0; j < 4; ++j)
      #pragma unroll
      for (int rr = 0; rr < 4; ++rr) {
        int m = mb + wr * 64 + i * 16 + 4 * g + rr;
        int jj = jb + wc * 64 + j * 16 + c;
        float v = acc[i][j][rr] + bias[2048 + m];
        VT[(size_t)bb * (1024 * 2048) + (size_t)m * 2048 + jj] = f2h(v);
      }
}

// ---------------- fused attention v9b: counted-vmcnt + sched_barrier fix ----------------
// Same as R17 v9, plus __builtin_amdgcn_sched_barrier(0) pinning each stage's
// register-only compute (MFMA/exp/pack) BEFORE the stage-end raw s_barrier
// (rule #18: memory clobber does not order register-only ops; without the pin,
// a wave can cross the barrier with ds_reads in flight while another wave's
// GLDS DMA overwrites the buffer).
__launch_bounds__(256, 3)
__global__ void k_attn_pv(const unsigned short* __restrict__ qf, const unsigned short* __restrict__ kf,
                          const unsigned short* __restrict__ VT, const float* __restrict__ posb,
                          float* __restrict__ attn, unsigned short* __restrict__ oc) {
  // h-major XCD chunking (R6-validated)
  const int swz = (int)((blockIdx.x & 7) * 512 + (blockIdx.x >> 3));
  const int h = swz >> 8;
  const int b = (swz >> 7) & 1;
  const int qt = swz & 127;

  const int t = threadIdx.x;
  const int wid = t >> 6, l = t & 63, g = l >> 4, c = l & 15;
  const int ct = wid;

  __shared__ unsigned smem[12288];       // S_k[3][2048] S_v[3][2048]
  __shared__ float lds_red[4][16];
  unsigned* S_k = smem;
  unsigned* S_v = smem + 6144;

  const size_t qoff = ((size_t)(qt * 16 + c) * 2 + b) * 1024 + h * 64 + g * 8;
  const f16x8 qfr0 = *(const f16x8*)(qf + qoff);
  const f16x8 qfr1 = *(const f16x8*)(qf + qoff + 32);

  const unsigned short* kfb = kf + (size_t)b * 1024 + h * 64;
  const unsigned short* vtb = VT + ((size_t)b * 1024 + h * 64) * 2048;
  const float* pbRow = posb + (size_t)b * S_ * S_ + (size_t)(qt * 16 + c) * S_ + ct * 16;

  const int rb = t >> 3;                 // 0..31
  const int lsl = (t & 7) ^ (rb & 7);    // pre-swizzled global slot

  #define LDSRD(base, row, slot) \
    __builtin_bit_cast(f16x8, *(const u32x4*)&(base)[(row) * 32 + ((((slot) ^ ((row) & 7))) * 4)])

  #define GLDS(stg, buf) do { \
    __builtin_amdgcn_global_load_lds( \
        (const __attribute__((address_space(1))) unsigned*)(kfb + (size_t)((stg) * 64 + rb) * 2048 + lsl * 8), \
        (__attribute__((address_space(3))) unsigned*)&S_k[(buf) * 2048 + wid * 256], 16, 0, 0); \
    __builtin_amdgcn_global_load_lds( \
        (const __attribute__((address_space(1))) unsigned*)(kfb + (size_t)((stg) * 64 + rb + 32) * 2048 + lsl * 8), \
        (__attribute__((address_space(3))) unsigned*)&S_k[(buf) * 2048 + 1024 + wid * 256], 16, 0, 0); \
    __builtin_amdgcn_global_load_lds( \
        (const __attribute__((address_space(1))) unsigned*)(vtb + (size_t)rb * 2048 + (stg) * 64 + lsl * 8), \
        (__attribute__((address_space(3))) unsigned*)&S_v[(buf) * 2048 + wid * 256], 16, 0, 0); \
    __builtin_amdgcn_global_load_lds( \
        (const __attribute__((address_space(1))) unsigned*)(vtb + (size_t)(rb + 32) * 2048 + (stg) * 64 + lsl * 8), \
        (__attribute__((address_space(3))) unsigned*)&S_v[(buf) * 2048 + 1024 + wid * 256], 16, 0, 0); \
  } while (0)

  // pin ALL preceding instructions (incl. register-only MFMA/exp/pack) before
  // the counted waitcnt + barrier; second sched_barrier stops hoisting from below.
  #define STAGEBAR(N) do { \
    __builtin_amdgcn_sched_barrier(0); \
    asm volatile("s_waitcnt vmcnt(" #N ")" ::: "memory"); \
    __builtin_amdgcn_s_barrier(); \
    __builtin_amdgcn_sched_barrier(0); \
  } while (0)

  f32x4 bias[2];
  unsigned psc0[32], psc1[32];
  float lsum = 0.f;
  f32x4 oacc[4] = {};

  // prologue: bias0, L0 -> buf0, L1 -> buf1; wait L0 (leave L1 in flight)
  {
    f32x4 b0 = *(const f32x4*)(pbRow + 4 * g);
    bias[0][0] = b0[0] - 8.f; bias[0][1] = b0[1] - 8.f;
    bias[0][2] = b0[2] - 8.f; bias[0][3] = b0[3] - 8.f;
  }
  GLDS(0, 0);
  GLDS(1, 1);
  STAGEBAR(4);

  #pragma unroll
  for (int st = 0; st < 32; ++st) {
    const int cur = st & 1;
    // bias for st+1 FIRST (older than this stage's GLDS batch)
    if (st < 31) {
      f32x4 bb = *(const f32x4*)(pbRow + (st + 1) * 64 + 4 * g);
      bias[cur ^ 1][0] = bb[0] - 8.f; bias[cur ^ 1][1] = bb[1] - 8.f;
      bias[cur ^ 1][2] = bb[2] - 8.f; bias[cur ^ 1][3] = bb[3] - 8.f;
    }
    // issue loads for st+2 (stay in flight across this stage's barrier)
    if (st < 30) GLDS(st + 2, (st + 2) % 3);

    // ---- QK(st): 2 MFMAs, independent chains ----
    {
      const int row = ct * 16 + c;
      const unsigned* kb = S_k + (st % 3) * 2048;
      f16x8 kfr0 = LDSRD(kb, row, g);
      f16x8 kfr1 = LDSRD(kb, row, 4 + g);
      f32x4 aA = {}, aB = {};
      aA = __builtin_amdgcn_mfma_f32_16x16x32_f16(kfr0, qfr0, aA, 0, 0, 0);
      aB = __builtin_amdgcn_mfma_f32_16x16x32_f16(kfr1, qfr1, aB, 0, 0, 0);
      float p0 = __expf(aA[0] + aB[0] + bias[cur][0]);
      float p1 = __expf(aA[1] + aB[1] + bias[cur][1]);
      float p2 = __expf(aA[2] + aB[2] + bias[cur][2]);
      float p3 = __expf(aA[3] + aB[3] + bias[cur][3]);
      lsum += (p0 + p1) + (p2 + p3);
      psc0[st] = pk_f16(p0, p1);
      psc1[st] = pk_f16(p2, p3);
    }

    // ---- PV(st): B from psc regs (fp16, K=16); A = V^T from LDS ----
    {
      u32x2 br; br[0] = psc0[st]; br[1] = psc1[st];
      const f16x4 bfrag = __builtin_bit_cast(f16x4, br);
      const unsigned* vb = S_v + (st % 3) * 2048;
      #pragma unroll
      for (int dt = 0; dt < 4; ++dt) {
        const int row = dt * 16 + c;
        const int sl = (2 * ct + (g >> 1)) ^ (row & 7);
        u32x2 ar = *(const u32x2*)&vb[row * 32 + sl * 4 + 2 * (g & 1)];
        oacc[dt] = __builtin_amdgcn_mfma_f32_16x16x16f16(__builtin_bit_cast(f16x4, ar), bfrag, oacc[dt], 0, 0, 0);
      }
    }

    // ---- pinned counted-vmcnt barrier ----
    if (st < 31) {
      if (st == 30) STAGEBAR(0);
      else          STAGEBAR(4);
    }
  }

  // ---- softmax denominator ----
  lsum += __shfl_xor(lsum, 16, 64);
  lsum += __shfl_xor(lsum, 32, 64);
  if (l < 16) lds_red[wid][l] = lsum;
  __syncthreads();
  const float inv = 1.0f / ((lds_red[0][c] + lds_red[1][c]) + (lds_red[2][c] + lds_red[3][c]));

  // ---- cross-wave out reduce (aliases staging LDS, stride 68) ----
  float* ored = (float*)smem;            // [4 waves][16 q][68]
  #pragma unroll
  for (int dt = 0; dt < 4; ++dt) {
    f32x4 o = oacc[dt];
    o[0] *= inv; o[1] *= inv; o[2] *= inv; o[3] *= inv;
    *(f32x4*)&ored[(wid * 16 + c) * 68 + dt * 16 + 4 * g] = o;
  }
  __syncthreads();
  {
    const int q = t >> 4;
    const int d0 = (t & 15) * 4;
    f32x4 s0 = *(const f32x4*)&ored[(0 * 16 + q) * 68 + d0];
    f32x4 s1 = *(const f32x4*)&ored[(1 * 16 + q) * 68 + d0];
    f32x4 s2 = *(const f32x4*)&ored[(2 * 16 + q) * 68 + d0];
    f32x4 s3 = *(const f32x4*)&ored[(3 * 16 + q) * 68 + d0];
    f32x4 s;
    s[0] = (s0[0] + s1[0]) + (s2[0] + s3[0]);
    s[1] = (s0[1] + s1[1]) + (s2[1] + s3[1]);
    s[2] = (s0[2] + s1[2]) + (s2[2] + s3[2]);
    s[3] = (s0[3] + s1[3]) + (s2[3] + s3[3]);
    u32x2 pk;
    pk[0] = pk_f16(s[0], s[1]);
    pk[1] = pk_f16(s[2], s[3]);
    *(u32x2*)&oc[((size_t)(qt * 16 + q) * 2 + b) * 1024 + h * 64 + d0] = pk;
  }

  // ---- attn write (normalized), unpack fp16 p ----
  float* arow = attn + ((size_t)(b * 16 + h) * S_ + qt * 16 + c) * S_ + ct * 16;
  #pragma unroll
  for (int st = 0; st < 32; ++st) {
    f16x2 h0 = __builtin_bit_cast(f16x2, psc0[st]);
    f16x2 h1 = __builtin_bit_cast(f16x2, psc1[st]);
    f32x4 o;
    o[0] = (float)h0[0] * inv;
    o[1] = (float)h0[1] * inv;
    o[2] = (float)h1[0] * inv;
    o[3] = (float)h1[1] * inv;
    *(f32x4*)(arow + (size_t)st * 64 + 4 * g) = o;
  }
  #undef LDSRD
  #undef GLDS
  #undef STAGEBAR
}

// ---------------- out projection (fp16) ----------------
__launch_bounds__(256, 2)
__global__ void k_outproj(const unsigned short* __restrict__ oc, const unsigned short* __restrict__ ow,
                          const float* __restrict__ ob, float* __restrict__ out) {
  __shared__ unsigned short sA[128][40], sB[128][40];
  const int t = threadIdx.x;
  const int wid = t >> 6, l = t & 63, g = l >> 4, c = l & 15;
  const int wr = wid >> 1, wc = wid & 1;
  const int mb = blockIdx.x * 128, nb = blockIdx.y * 128;
  const int sr = t >> 1, sc = (t & 1) * 16;

  f32x4 acc[4][4] = {};
  for (int k0 = 0; k0 < 1024; k0 += 32) {
    __syncthreads();
    {
      const unsigned short* pa = oc + (size_t)(mb + sr) * 1024 + k0 + sc;
      const unsigned short* pb = ow + (size_t)(nb + sr) * 1024 + k0 + sc;
      *(f16x8*)&sA[sr][sc]     = *(const f16x8*)pa;
      *(f16x8*)&sA[sr][sc + 8] = *(const f16x8*)(pa + 8);
      *(f16x8*)&sB[sr][sc]     = *(const f16x8*)pb;
      *(f16x8*)&sB[sr][sc + 8] = *(const f16x8*)(pb + 8);
    }
    __syncthreads();
    f16x8 af[4], bf[4];
    #pragma unroll
    for (int i = 0; i < 4; ++i) {
      af[i] = *(const f16x8*)&sA[wr * 64 + i * 16 + c][g * 8];
      bf[i] = *(const f16x8*)&sB[wc * 64 + i * 16 + c][g * 8];
    }
    #pragma unroll
    for (int i = 0; i < 4; ++i)
      #pragma unroll
      for (int j = 0; j < 4; ++j)
        acc[i][j] = __builtin_amdgcn_mfma_f32_16x16x32_f16(af[i], bf[j], acc[i][j], 0, 0, 0);
  }
  #pragma unroll
  for (int i = 0; i < 4; ++i)
    #pragma unroll
    for (int j = 0; j < 4; ++j)
      #pragma unroll
      for (int rr = 0; rr < 4; ++rr) {
        int m = mb + wr * 64 + i * 16 + 4 * g + rr;
        int n = nb + wc * 64 + j * 16 + c;
        out[(size_t)m * 1024 + n] = acc[i][j][rr] + ob[n];
      }
}

extern "C" void kernel_launch(void* const* d_in, const int* in_sizes, int n_in,
                              void* d_out, int out_size, void* d_ws, size_t ws_size,
                              hipStream_t stream) {
  (void)in_sizes; (void)n_in; (void)out_size; (void)ws_size;
  const float* query = (const float*)d_in[0];
  const float* keyi  = (const float*)d_in[1];
  const float* value = (const float*)d_in[2];
  const float* posb  = (const float*)d_in[3];
  const float* ipw   = (const float*)d_in[4];
  const float* ipb   = (const float*)d_in[5];
  const float* outw  = (const float*)d_in[6];
  const float* outb  = (const float*)d_in[7];
  float* out = (float*)d_out;
  float* attn = out + (size_t)S_ * B_ * E_;

  char* ws = (char*)d_ws;
  size_t off = 0;
  auto alloc = [&](size_t bytes) -> void* {
    void* p = ws + off;
    off += (bytes + 255) & ~(size_t)255;
    return p;
  };
  const size_t NTOK = (size_t)S_ * B_;  // 4096
  unsigned short* qx  = (unsigned short*)alloc(NTOK * 1024 * 2);
  unsigned short* kx  = (unsigned short*)alloc(NTOK * 1024 * 2);
  unsigned short* vx  = (unsigned short*)alloc(NTOK * 1024 * 2);
  unsigned short* w3  = (unsigned short*)alloc((size_t)3072 * 1024 * 2);
  unsigned short* ow  = (unsigned short*)alloc((size_t)1024 * 1024 * 2);
  unsigned short* qf  = (unsigned short*)alloc(NTOK * 1024 * 2);
  unsigned short* kf  = (unsigned short*)alloc(NTOK * 1024 * 2);
  unsigned short* VT  = (unsigned short*)alloc((size_t)2 * 1024 * 2048 * 2);
  unsigned short* oc  = (unsigned short*)alloc(NTOK * 1024 * 2);

  k_cvt_all<<<2048, 256, 0, stream>>>(query, keyi, value, ipw, outw, qx, kx, vx, w3, ow);

  k_proj_qk<<<dim3(32, 8, 2), 256, 0, stream>>>(qx, kx, w3, ipb, qf, kf);
  k_proj_v<<<dim3(8, 32), 256, 0, stream>>>(w3 + (size_t)2048 * 1024, vx, ipb, VT);
  k_attn_pv<<<4096, 256, 0, stream>>>(qf, kf, VT, posb, attn, oc);
  k_outproj<<<dim3(32, 8), 256, 0, stream>>>(oc, ow, outb, out);
}

// Round 19
// 354.900 us; speedup vs baseline: 1.0660x; 1.0660x over previous
//
#include <hip/hip_runtime.h>

#define S_ 2048
#define B_ 2
#define E_ 1024
#define H_ 16

typedef _Float16 f16x8 __attribute__((ext_vector_type(8)));
typedef _Float16 f16x4 __attribute__((ext_vector_type(4)));
typedef _Float16 f16x2 __attribute__((ext_vector_type(2)));
typedef float f32x4 __attribute__((ext_vector_type(4)));
typedef unsigned short us4_t __attribute__((ext_vector_type(4)));
typedef unsigned u32x4 __attribute__((ext_vector_type(4)));
typedef unsigned u32x2 __attribute__((ext_vector_type(2)));

static __device__ __forceinline__ unsigned short f2h(float x) {
  _Float16 h = (_Float16)x;   // RNE
  return __builtin_bit_cast(unsigned short, h);
}
static __device__ __forceinline__ unsigned pk_f16(float a, float b) {
  auto r = __builtin_amdgcn_cvt_pkrtz(a, b);   // lo=a, hi=b (RTZ - p only)
  return __builtin_bit_cast(unsigned, r);
}

// ---------------- all f32 -> fp16 conversions in ONE launch (RNE) ----------------
// vec4 segments: q 1M | k 1M | v 1M | ipw 768K | outw 256K | posb 2M = 6M total
__global__ void k_cvt_all(const float* __restrict__ q, const float* __restrict__ k,
                          const float* __restrict__ v, const float* __restrict__ ipw,
                          const float* __restrict__ outw, const float* __restrict__ posb,
                          unsigned short* __restrict__ qx, unsigned short* __restrict__ kx,
                          unsigned short* __restrict__ vx, unsigned short* __restrict__ w3,
                          unsigned short* __restrict__ ow, unsigned short* __restrict__ pb16) {
  const int M1 = 1 << 20;
  int i = blockIdx.x * blockDim.x + threadIdx.x;
  int stp = gridDim.x * blockDim.x;
  for (; i < 6 * M1; i += stp) {
    const float* src;
    unsigned short* dst;
    int j;
    if (i < M1)                   { src = q;    dst = qx;   j = i; }
    else if (i < 2 * M1)          { src = k;    dst = kx;   j = i - M1; }
    else if (i < 3 * M1)          { src = v;    dst = vx;   j = i - 2 * M1; }
    else if (i < 3 * M1 + 786432) { src = ipw;  dst = w3;   j = i - 3 * M1; }
    else if (i < 4 * M1)          { src = outw; dst = ow;   j = i - 3 * M1 - 786432; }
    else                          { src = posb; dst = pb16; j = i - 4 * M1; }
    f32x4 x = ((const f32x4*)src)[j];
    us4_t h;
    #pragma unroll
    for (int e = 0; e < 4; ++e) h[e] = f2h(x[e]);
    ((us4_t*)dst)[j] = h;
  }
}

// ---------------- q/k projection: plain fp16 GEMM ----------------
__launch_bounds__(256, 2)
__global__ void k_proj_qk(const unsigned short* __restrict__ qx, const unsigned short* __restrict__ kx,
                          const unsigned short* __restrict__ wqk, const float* __restrict__ bias,
                          unsigned short* __restrict__ qf, unsigned short* __restrict__ kf) {
  const int z = blockIdx.z;
  const unsigned short* A = z ? kx : qx;
  const unsigned short* W = wqk + (size_t)z * (1024 * 1024);
  unsigned short* C = z ? kf : qf;
  const float* bia = bias + z * 1024;
  const float scale = z ? 1.0f : 0.125f;

  __shared__ unsigned short sA[128][40], sB[128][40];

  const int t = threadIdx.x;
  const int wid = t >> 6, l = t & 63, g = l >> 4, c = l & 15;
  const int wr = wid >> 1, wc = wid & 1;
  const int mb = blockIdx.x * 128, nb = blockIdx.y * 128;
  const int sr = t >> 1, sc = (t & 1) * 16;

  f32x4 acc[4][4] = {};

  for (int k0 = 0; k0 < 1024; k0 += 32) {
    __syncthreads();
    {
      const unsigned short* pa = A + (size_t)(mb + sr) * 1024 + k0 + sc;
      const unsigned short* pb = W + (size_t)(nb + sr) * 1024 + k0 + sc;
      *(f16x8*)&sA[sr][sc]     = *(const f16x8*)pa;
      *(f16x8*)&sA[sr][sc + 8] = *(const f16x8*)(pa + 8);
      *(f16x8*)&sB[sr][sc]     = *(const f16x8*)pb;
      *(f16x8*)&sB[sr][sc + 8] = *(const f16x8*)(pb + 8);
    }
    __syncthreads();
    f16x8 af[4], bf[4];
    #pragma unroll
    for (int i = 0; i < 4; ++i) {
      af[i] = *(const f16x8*)&sA[wr * 64 + i * 16 + c][g * 8];
      bf[i] = *(const f16x8*)&sB[wc * 64 + i * 16 + c][g * 8];
    }
    #pragma unroll
    for (int i = 0; i < 4; ++i)
      #pragma unroll
      for (int j = 0; j < 4; ++j)
        acc[i][j] = __builtin_amdgcn_mfma_f32_16x16x32_f16(af[i], bf[j], acc[i][j], 0, 0, 0);
  }
  #pragma unroll
  for (int i = 0; i < 4; ++i)
    #pragma unroll
    for (int j = 0; j < 4; ++j)
      #pragma unroll
      for (int rr = 0; rr < 4; ++rr) {
        int m = mb + wr * 64 + i * 16 + 4 * g + rr;
        int n = nb + wc * 64 + j * 16 + c;
        float v = (acc[i][j][rr] + bia[n]) * scale;
        C[(size_t)m * 1024 + n] = f2h(v);
      }
}

// ---------------- v projection (fp16), writes V^T: VT[b][e'][j] ----------------
__launch_bounds__(256, 2)
__global__ void k_proj_v(const unsigned short* __restrict__ wv, const unsigned short* __restrict__ vx,
                         const float* __restrict__ bias, unsigned short* __restrict__ VT) {
  __shared__ unsigned short sA[128][40], sB[128][40];
  const int t = threadIdx.x;
  const int wid = t >> 6, l = t & 63, g = l >> 4, c = l & 15;
  const int wr = wid >> 1, wc = wid & 1;
  const int mb = blockIdx.x * 128;   // e' base
  const int nb = blockIdx.y * 128;   // n = b*2048 + j
  const int bb = nb >> 11;
  const int jb = nb & 2047;
  const int sr = t >> 1, sc = (t & 1) * 16;

  f32x4 acc[4][4] = {};
  for (int k0 = 0; k0 < 1024; k0 += 32) {
    __syncthreads();
    {
      const unsigned short* pa = wv + (size_t)(mb + sr) * 1024 + k0 + sc;
      const unsigned short* pb = vx + ((size_t)(jb + sr) * 2 + bb) * 1024 + k0 + sc;
      *(f16x8*)&sA[sr][sc]     = *(const f16x8*)pa;
      *(f16x8*)&sA[sr][sc + 8] = *(const f16x8*)(pa + 8);
      *(f16x8*)&sB[sr][sc]     = *(const f16x8*)pb;
      *(f16x8*)&sB[sr][sc + 8] = *(const f16x8*)(pb + 8);
    }
    __syncthreads();
    f16x8 af[4], bf[4];
    #pragma unroll
    for (int i = 0; i < 4; ++i) {
      af[i] = *(const f16x8*)&sA[wr * 64 + i * 16 + c][g * 8];
      bf[i] = *(const f16x8*)&sB[wc * 64 + i * 16 + c][g * 8];
    }
    #pragma unroll
    for (int i = 0; i < 4; ++i)
      #pragma unroll
      for (int j = 0; j < 4; ++j)
        acc[i][j] = __builtin_amdgcn_mfma_f32_16x16x32_f16(af[i], bf[j], acc[i][j], 0, 0, 0);
  }
  #pragma unroll
  for (int i = 0; i < 4; ++i)
    #pragma unroll
    for (int j = 0; j < 4; ++j)
      #pragma unroll
      for (int rr = 0; rr < 4; ++rr) {
        int m = mb + wr * 64 + i * 16 + 4 * g + rr;
        int jj = jb + wc * 64 + j * 16 + c;
        float v = acc[i][j][rr] + bias[2048 + m];
        VT[(size_t)bb * (1024 * 2048) + (size_t)m * 2048 + jj] = f2h(v);
      }
}

// ---------------- fused attention v8b: R16 structure + fp16 posb ----------------
// Block=(b,h,qt), 256 thr = 4 waves; wave ct owns cols ct*16 of each KVBLK=64.
// QK: 2x mfma_f32_16x16x32_f16; acc@(g,c)=s[k=4g+rr][q=c] == B-frag of K=16
// MFMA -> PV B direct from packed fp16 p regs. p = exp(s-8) (cancels in norm).
// Staging: global_load_lds w=16, linear LDS dest (wave base + lane*16B), XOR
// swizzle folded into per-lane GLOBAL source slot (rule #21). Loads for st+1
// issue at stage-st top; stage-end __syncthreads drains them (R16-verified).
// posb read as fp16 (half the bias bytes; better L3 survival).
__launch_bounds__(256, 4)
__global__ void k_attn_pv(const unsigned short* __restrict__ qf, const unsigned short* __restrict__ kf,
                          const unsigned short* __restrict__ VT, const unsigned short* __restrict__ pb16,
                          float* __restrict__ attn, unsigned short* __restrict__ oc) {
  // h-major XCD chunking (R6-validated)
  const int swz = (int)((blockIdx.x & 7) * 512 + (blockIdx.x >> 3));
  const int h = swz >> 8;
  const int b = (swz >> 7) & 1;
  const int qt = swz & 127;

  const int t = threadIdx.x;
  const int wid = t >> 6, l = t & 63, g = l >> 4, c = l & 15;
  const int ct = wid;

  __shared__ unsigned smem[8192];        // S_k[2][2048] S_v[2][2048]
  __shared__ float lds_red[4][16];
  unsigned* S_k = smem;
  unsigned* S_v = smem + 4096;

  const size_t qoff = ((size_t)(qt * 16 + c) * 2 + b) * 1024 + h * 64 + g * 8;
  const f16x8 qfr0 = *(const f16x8*)(qf + qoff);
  const f16x8 qfr1 = *(const f16x8*)(qf + qoff + 32);

  const unsigned short* kfb = kf + (size_t)b * 1024 + h * 64;
  const unsigned short* vtb = VT + ((size_t)b * 1024 + h * 64) * 2048;
  const unsigned short* pbRow = pb16 + (size_t)b * S_ * S_ + (size_t)(qt * 16 + c) * S_ + ct * 16;

  const int rb = t >> 3;                 // 0..31
  const int lsl = (t & 7) ^ (rb & 7);    // pre-swizzled global slot

  #define LDSRD(base, row, slot) \
    __builtin_bit_cast(f16x8, *(const u32x4*)&(base)[(row) * 32 + ((((slot) ^ ((row) & 7))) * 4)])

  #define GLDS(stg, buf) do { \
    __builtin_amdgcn_global_load_lds( \
        (const __attribute__((address_space(1))) unsigned*)(kfb + (size_t)((stg) * 64 + rb) * 2048 + lsl * 8), \
        (__attribute__((address_space(3))) unsigned*)&S_k[(buf) * 2048 + wid * 256], 16, 0, 0); \
    __builtin_amdgcn_global_load_lds( \
        (const __attribute__((address_space(1))) unsigned*)(kfb + (size_t)((stg) * 64 + rb + 32) * 2048 + lsl * 8), \
        (__attribute__((address_space(3))) unsigned*)&S_k[(buf) * 2048 + 1024 + wid * 256], 16, 0, 0); \
    __builtin_amdgcn_global_load_lds( \
        (const __attribute__((address_space(1))) unsigned*)(vtb + (size_t)rb * 2048 + (stg) * 64 + lsl * 8), \
        (__attribute__((address_space(3))) unsigned*)&S_v[(buf) * 2048 + wid * 256], 16, 0, 0); \
    __builtin_amdgcn_global_load_lds( \
        (const __attribute__((address_space(1))) unsigned*)(vtb + (size_t)(rb + 32) * 2048 + (stg) * 64 + lsl * 8), \
        (__attribute__((address_space(3))) unsigned*)&S_v[(buf) * 2048 + 1024 + wid * 256], 16, 0, 0); \
  } while (0)

  f32x4 bias[2];
  unsigned psc0[32], psc1[32];
  float lsum = 0.f;
  f32x4 oacc[4] = {};

  // prologue: stage 0 -> buf 0; bias0 (fp16 -> f32, minus 8)
  GLDS(0, 0);
  {
    f16x4 b0 = *(const f16x4*)(pbRow + 4 * g);
    bias[0][0] = (float)b0[0] - 8.f; bias[0][1] = (float)b0[1] - 8.f;
    bias[0][2] = (float)b0[2] - 8.f; bias[0][3] = (float)b0[3] - 8.f;
  }
  __syncthreads();   // drains vmcnt -> buf0 ready

  #pragma unroll
  for (int st = 0; st < 32; ++st) {
    const int cur = st & 1;
    // issue loads for st+1 into buf^1 (read last at st-1; barrier separated)
    if (st < 31) GLDS(st + 1, cur ^ 1);
    if (st < 31) {
      f16x4 bb = *(const f16x4*)(pbRow + (st + 1) * 64 + 4 * g);
      bias[cur ^ 1][0] = (float)bb[0] - 8.f; bias[cur ^ 1][1] = (float)bb[1] - 8.f;
      bias[cur ^ 1][2] = (float)bb[2] - 8.f; bias[cur ^ 1][3] = (float)bb[3] - 8.f;
    }

    // ---- QK(st): 2 MFMAs, independent chains ----
    {
      const int row = ct * 16 + c;
      const unsigned* kb = S_k + cur * 2048;
      f16x8 kfr0 = LDSRD(kb, row, g);
      f16x8 kfr1 = LDSRD(kb, row, 4 + g);
      f32x4 aA = {}, aB = {};
      aA = __builtin_amdgcn_mfma_f32_16x16x32_f16(kfr0, qfr0, aA, 0, 0, 0);
      aB = __builtin_amdgcn_mfma_f32_16x16x32_f16(kfr1, qfr1, aB, 0, 0, 0);
      float p0 = __expf(aA[0] + aB[0] + bias[cur][0]);
      float p1 = __expf(aA[1] + aB[1] + bias[cur][1]);
      float p2 = __expf(aA[2] + aB[2] + bias[cur][2]);
      float p3 = __expf(aA[3] + aB[3] + bias[cur][3]);
      lsum += (p0 + p1) + (p2 + p3);
      psc0[st] = pk_f16(p0, p1);
      psc1[st] = pk_f16(p2, p3);
    }

    // ---- PV(st): B from psc regs (fp16, K=16); A = V^T from LDS ----
    {
      u32x2 br; br[0] = psc0[st]; br[1] = psc1[st];
      const f16x4 bfrag = __builtin_bit_cast(f16x4, br);
      const unsigned* vb = S_v + cur * 2048;
      #pragma unroll
      for (int dt = 0; dt < 4; ++dt) {
        const int row = dt * 16 + c;
        const int sl = (2 * ct + (g >> 1)) ^ (row & 7);
        u32x2 ar = *(const u32x2*)&vb[row * 32 + sl * 4 + 2 * (g & 1)];
        oacc[dt] = __builtin_amdgcn_mfma_f32_16x16x16f16(__builtin_bit_cast(f16x4, ar), bfrag, oacc[dt], 0, 0, 0);
      }
    }

    __syncthreads();   // drains vmcnt (st+1 loads) + orders buf reuse
  }

  // ---- softmax denominator ----
  lsum += __shfl_xor(lsum, 16, 64);
  lsum += __shfl_xor(lsum, 32, 64);
  if (l < 16) lds_red[wid][l] = lsum;
  __syncthreads();
  const float inv = 1.0f / ((lds_red[0][c] + lds_red[1][c]) + (lds_red[2][c] + lds_red[3][c]));

  // ---- cross-wave out reduce (aliases staging LDS, stride 68) ----
  float* ored = (float*)smem;            // [4 waves][16 q][68]
  #pragma unroll
  for (int dt = 0; dt < 4; ++dt) {
    f32x4 o = oacc[dt];
    o[0] *= inv; o[1] *= inv; o[2] *= inv; o[3] *= inv;
    *(f32x4*)&ored[(wid * 16 + c) * 68 + dt * 16 + 4 * g] = o;
  }
  __syncthreads();
  {
    const int q = t >> 4;
    const int d0 = (t & 15) * 4;
    f32x4 s0 = *(const f32x4*)&ored[(0 * 16 + q) * 68 + d0];
    f32x4 s1 = *(const f32x4*)&ored[(1 * 16 + q) * 68 + d0];
    f32x4 s2 = *(const f32x4*)&ored[(2 * 16 + q) * 68 + d0];
    f32x4 s3 = *(const f32x4*)&ored[(3 * 16 + q) * 68 + d0];
    f32x4 s;
    s[0] = (s0[0] + s1[0]) + (s2[0] + s3[0]);
    s[1] = (s0[1] + s1[1]) + (s2[1] + s3[1]);
    s[2] = (s0[2] + s1[2]) + (s2[2] + s3[2]);
    s[3] = (s0[3] + s1[3]) + (s2[3] + s3[3]);
    u32x2 pk;
    pk[0] = pk_f16(s[0], s[1]);
    pk[1] = pk_f16(s[2], s[3]);
    *(u32x2*)&oc[((size_t)(qt * 16 + q) * 2 + b) * 1024 + h * 64 + d0] = pk;
  }

  // ---- attn write (normalized), unpack fp16 p ----
  float* arow = attn + ((size_t)(b * 16 + h) * S_ + qt * 16 + c) * S_ + ct * 16;
  #pragma unroll
  for (int st = 0; st < 32; ++st) {
    f16x2 h0 = __builtin_bit_cast(f16x2, psc0[st]);
    f16x2 h1 = __builtin_bit_cast(f16x2, psc1[st]);
    f32x4 o;
    o[0] = (float)h0[0] * inv;
    o[1] = (float)h0[1] * inv;
    o[2] = (float)h1[0] * inv;
    o[3] = (float)h1[1] * inv;
    *(f32x4*)(arow + (size_t)st * 64 + 4 * g) = o;
  }
  #undef LDSRD
  #undef GLDS
}

// ---------------- out projection (fp16) ----------------
__launch_bounds__(256, 2)
__global__ void k_outproj(const unsigned short* __restrict__ oc, const unsigned short* __restrict__ ow,
                          const float* __restrict__ ob, float* __restrict__ out) {
  __shared__ unsigned short sA[128][40], sB[128][40];
  const int t = threadIdx.x;
  const int wid = t >> 6, l = t & 63, g = l >> 4, c = l & 15;
  const int wr = wid >> 1, wc = wid & 1;
  const int mb = blockIdx.x * 128, nb = blockIdx.y * 128;
  const int sr = t >> 1, sc = (t & 1) * 16;

  f32x4 acc[4][4] = {};
  for (int k0 = 0; k0 < 1024; k0 += 32) {
    __syncthreads();
    {
      const unsigned short* pa = oc + (size_t)(mb + sr) * 1024 + k0 + sc;
      const unsigned short* pb = ow + (size_t)(nb + sr) * 1024 + k0 + sc;
      *(f16x8*)&sA[sr][sc]     = *(const f16x8*)pa;
      *(f16x8*)&sA[sr][sc + 8] = *(const f16x8*)(pa + 8);
      *(f16x8*)&sB[sr][sc]     = *(const f16x8*)pb;
      *(f16x8*)&sB[sr][sc + 8] = *(const f16x8*)(pb + 8);
    }
    __syncthreads();
    f16x8 af[4], bf[4];
    #pragma unroll
    for (int i = 0; i < 4; ++i) {
      af[i] = *(const f16x8*)&sA[wr * 64 + i * 16 + c][g * 8];
      bf[i] = *(const f16x8*)&sB[wc * 64 + i * 16 + c][g * 8];
    }
    #pragma unroll
    for (int i = 0; i < 4; ++i)
      #pragma unroll
      for (int j = 0; j < 4; ++j)
        acc[i][j] = __builtin_amdgcn_mfma_f32_16x16x32_f16(af[i], bf[j], acc[i][j], 0, 0, 0);
  }
  #pragma unroll
  for (int i = 0; i < 4; ++i)
    #pragma unroll
    for (int j = 0; j < 4; ++j)
      #pragma unroll
      for (int rr = 0; rr < 4; ++rr) {
        int m = mb + wr * 64 + i * 16 + 4 * g + rr;
        int n = nb + wc * 64 + j * 16 + c;
        out[(size_t)m * 1024 + n] = acc[i][j][rr] + ob[n];
      }
}

extern "C" void kernel_launch(void* const* d_in, const int* in_sizes, int n_in,
                              void* d_out, int out_size, void* d_ws, size_t ws_size,
                              hipStream_t stream) {
  (void)in_sizes; (void)n_in; (void)out_size; (void)ws_size;
  const float* query = (const float*)d_in[0];
  const float* keyi  = (const float*)d_in[1];
  const float* value = (const float*)d_in[2];
  const float* posb  = (const float*)d_in[3];
  const float* ipw   = (const float*)d_in[4];
  const float* ipb   = (const float*)d_in[5];
  const float* outw  = (const float*)d_in[6];
  const float* outb  = (const float*)d_in[7];
  float* out = (float*)d_out;
  float* attn = out + (size_t)S_ * B_ * E_;

  char* ws = (char*)d_ws;
  size_t off = 0;
  auto alloc = [&](size_t bytes) -> void* {
    void* p = ws + off;
    off += (bytes + 255) & ~(size_t)255;
    return p;
  };
  const size_t NTOK = (size_t)S_ * B_;  // 4096
  unsigned short* qx   = (unsigned short*)alloc(NTOK * 1024 * 2);
  unsigned short* kx   = (unsigned short*)alloc(NTOK * 1024 * 2);
  unsigned short* vx   = (unsigned short*)alloc(NTOK * 1024 * 2);
  unsigned short* w3   = (unsigned short*)alloc((size_t)3072 * 1024 * 2);
  unsigned short* ow   = (unsigned short*)alloc((size_t)1024 * 1024 * 2);
  unsigned short* pb16 = (unsigned short*)alloc((size_t)B_ * S_ * S_ * 2);
  unsigned short* qf   = (unsigned short*)alloc(NTOK * 1024 * 2);
  unsigned short* kf   = (unsigned short*)alloc(NTOK * 1024 * 2);
  unsigned short* VT   = (unsigned short*)alloc((size_t)2 * 1024 * 2048 * 2);
  unsigned short* oc   = (unsigned short*)alloc(NTOK * 1024 * 2);

  k_cvt_all<<<3072, 256, 0, stream>>>(query, keyi, value, ipw, outw, posb,
                                      qx, kx, vx, w3, ow, pb16);

  k_proj_qk<<<dim3(32, 8, 2), 256, 0, stream>>>(qx, kx, w3, ipb, qf, kf);
  k_proj_v<<<dim3(8, 32), 256, 0, stream>>>(w3 + (size_t)2048 * 1024, vx, ipb, VT);
  k_attn_pv<<<4096, 256, 0, stream>>>(qf, kf, VT, pb16, attn, oc);
  k_outproj<<<dim3(32, 8), 256, 0, stream>>>(oc, ow, outb, out);
}